// Round 3
// baseline (10.245 us; speedup 1.0000x reference)
//
#include <hip/hip_runtime.h>

#define INF_VAL 100000000.0f

#define N0 65536
#define N1 32768
#define N2 16384
#define NTOT (N0 + N1 + N2)
#define M_ANN 512

__global__ __launch_bounds__(256) void assign_scatter_kernel(
    const float* __restrict__ ann,   // [512,3] (l, r, c)
    const float* __restrict__ a0,    // [65536]
    const float* __restrict__ a1,    // [32768]
    const float* __restrict__ a2,    // [16384]
    float* __restrict__ out)         // [12 * NTOT]
{
    const int t = threadIdx.x;
    const int b = blockIdx.x;

    // Block-uniform level resolution (each block lies entirely in one level).
    int level, bbase;                       // bbase = block's first LOCAL anchor idx
    const float* __restrict__ anch;
    if (b < N0 / 256)              { level = 0; bbase = b * 256;                    anch = a0; }
    else if (b < (N0 + N1) / 256)  { level = 1; bbase = (b - N0/256) * 256;         anch = a1; }
    else                           { level = 2; bbase = (b - (N0+N1)/256) * 256;    anch = a2; }

    const float stride = (float)(1 << level);
    const float inv_stride = 1.0f / stride;      // power of 2: exact

    // Thresholds: replicate JAX weak-type promotion — double product, cast to f32.
    const double TR = 22050.0 / 256.0;           // 86.1328125
    float lo_t, hi_t;
    if (level == 0)      { lo_t = (float)(-1.0  * TR); hi_t = (float)(0.45   * TR); }
    else if (level == 1) { lo_t = (float)(0.45  * TR); hi_t = (float)(0.9    * TR); }
    else                 { lo_t = (float)(0.9   * TR); hi_t = (float)(1000.0 * TR); }

    __shared__ float s_l[M_ANN], s_r[M_ANN], s_c[M_ANN];
    __shared__ unsigned long long s_key[256];    // (area_bits << 32) | j, min = best

    s_key[t] = ~0ull;
    __syncthreads();                             // init visible before any atomicMin

    // Scatter: each thread owns annotations t and t+256. A valid (anchor, j)
    // pair needs l_j <= a <= min(r_j, l_j + radius_j*stride), so each
    // annotation covers a short contiguous run of grid anchors. Conservative
    // integer range (widened +-1), every candidate re-tested with the EXACT
    // reference predicates; atomicMin on (area_bits, j) = first-index argmin.
    for (int j = t; j < M_ANN; j += 256) {
        float l = ann[j * 3 + 0];
        float r = ann[j * 3 + 1];
        float c = ann[j * 3 + 2];
        s_l[j] = l; s_r[j] = r; s_c[j] = c;

        float radius = (c == 0.0f) ? 4.5f : ((c == 1.0f) ? 2.5f : 0.0f);
        float rl = l + radius * stride;          // radius_limit, same order as ref
        float ub = fminf(r, rl);

        int i0 = (int)ceilf(l  * inv_stride - 0.5f) - 1;   // a_i=(i+0.5)*stride >= l
        int i1 = (int)floorf(ub * inv_stride - 0.5f) + 1;  // a_i <= ub
        int lo = i0 > bbase ? i0 : bbase;
        int hi = i1 < bbase + 255 ? i1 : bbase + 255;

        unsigned long long key =
            ((unsigned long long)__float_as_uint(r - l) << 32) | (unsigned)j;

        for (int i = lo; i <= hi; ++i) {
            float a = ((float)i + 0.5f) * stride;          // bitwise == input anchors
            float m = fmaxf(a - l, r - a);
            bool valid = (a >= l) & (a <= ub) & (m >= lo_t) & (m <= hi_t);
            if (valid) atomicMin(&s_key[i - bbase], key);
        }
    }
    __syncthreads();

    // Gather: O(1) per anchor.
    const int g = b * 256 + t;                   // global (concatenated) anchor idx
    const float a = anch[bbase + t];

    const unsigned long long key = s_key[t];
    const bool pos = (key != ~0ull);
    const int bidx = pos ? (int)(key & 0xFFFFFFFFu) : 0;

    const float l = s_l[bidx];
    const float r = s_r[bidx];
    const float cc = pos ? s_c[bidx] : 0.0f;
    const float ls = a - l;
    const float rs = r - a;

    out[g]                    = pos ? 1.0f : 0.0f;        // pos
    out[NTOT     + g * 3 + 0] = l;                        // assigned
    out[NTOT     + g * 3 + 1] = r;
    out[NTOT     + g * 3 + 2] = cc;
    out[4 * NTOT + g * 3 + 0] = l * inv_stride;           // normalized
    out[4 * NTOT + g * 3 + 1] = r * inv_stride;
    out[4 * NTOT + g * 3 + 2] = cc;
    out[7 * NTOT  + g] = ls;                              // l_star
    out[8 * NTOT  + g] = rs;                              // r_star
    out[9 * NTOT  + g] = ls * inv_stride;                 // nl_star
    out[10 * NTOT + g] = rs * inv_stride;                 // nr_star
    out[11 * NTOT + g] = (float)(level + 1);              // levels
}

extern "C" void kernel_launch(void* const* d_in, const int* in_sizes, int n_in,
                              void* d_out, int out_size, void* d_ws, size_t ws_size,
                              hipStream_t stream) {
    const float* ann = (const float*)d_in[0];
    const float* a0  = (const float*)d_in[1];
    const float* a1  = (const float*)d_in[2];
    const float* a2  = (const float*)d_in[3];
    float* out = (float*)d_out;

    const int blocks = NTOT / 256;  // 448
    assign_scatter_kernel<<<blocks, 256, 0, stream>>>(ann, a0, a1, a2, out);
}